// Round 8
// baseline (27.399 us; speedup 1.0000x reference)
//
#include <hip/hip_runtime.h>
#include <hip/hip_fp8.h>

#define NN 4096
#define DD 512
#define CC 1000
#define NB 64   // 64 row/col panels of 64 rows -> triangle = 2080 tiles

typedef __attribute__((ext_vector_type(4))) float f32x4;

// ---------------- kernel 1: normalize rows -> fp8 e4m3 X, init out ---------
__global__ __launch_bounds__(256) void knorm(const float* __restrict__ embs,
                                             unsigned char* __restrict__ Xq,
                                             float* __restrict__ out) {
  int tid = threadIdx.x;
  if (blockIdx.x == 0 && tid == 0) out[0] = 0.f;  // stream-ordered before kmain
  int lane = tid & 63;
  int row = blockIdx.x * 4 + (tid >> 6);
  const float* rp = embs + (size_t)row * DD;
  float4 v0 = ((const float4*)rp)[lane * 2];
  float4 v1 = ((const float4*)rp)[lane * 2 + 1];
  float ss = v0.x * v0.x + v0.y * v0.y + v0.z * v0.z + v0.w * v0.w +
             v1.x * v1.x + v1.y * v1.y + v1.z * v1.z + v1.w * v1.w;
  for (int off = 32; off; off >>= 1) ss += __shfl_xor(ss, off);
  float scale = 1.0f / fmaxf(sqrtf(ss), 1e-8f);
  float f[8] = {v0.x, v0.y, v0.z, v0.w, v1.x, v1.y, v1.z, v1.w};
  unsigned long long o = 0;
#pragma unroll
  for (int i = 0; i < 8; ++i) {
    __hip_fp8_e4m3 q(f[i] * scale);  // OCP e4m3fn, RNE
    o |= (unsigned long long)q.__x << (8 * i);
  }
  *(unsigned long long*)(Xq + (size_t)row * DD + lane * 8) = o;
}

// ---------------- kernel 2: chunked triangular fp8 X @ X^T -> gated loss ----
// 512 blocks, each owns 4-5 CONSECUTIVE tiles of a 65-tile "super-row"
// (row sr paired with row 63-sr for perfect balance). Full-K panels in LDS
// (A,B = 32KB each, 64KB total -> 2 blocks/CU): ONE stage->drain per tile,
// A-panel restaged only when the row-panel changes (<=2x per block).
// Compute per tile is barrier-free: 16 k-chunks x 4 mfma_f32_16x16x32_fp8_fp8.
// Swizzle family from R7 (proven): stage source byte ((c ^ (r&7))<<4), read
// byte (((q ^ (r&7))<<4)|o) -- rows are 512B, XOR touches only bits 4-6.
// Per-element triangle rule: col>row -> both ordered terms (mirrored Aij
// gather); col==row -> single term (in-MFMA diagonal); col<row skipped.
__global__ __launch_bounds__(256) void kmain(const unsigned char* __restrict__ Xq,
                                             const int* __restrict__ labels,
                                             const float* __restrict__ Aij,
                                             float* __restrict__ out) {
  __shared__ __align__(16) unsigned char As[64 * 512];  // full A panel (32 KB)
  __shared__ __align__(16) unsigned char Bs[64 * 512];  // full B panel (32 KB)
  int tid = threadIdx.x;
  int lane = tid & 63;
  int w = tid >> 6;
  int wr = w >> 1, wc = w & 1;

  // chunk assignment: super-row sr = rows {sr, 63-sr}, 65 tiles, 16 blocks
  int sr = blockIdx.x >> 4;
  int slot = blockIdx.x & 15;
  int start = slot ? 5 + (slot - 1) * 4 : 0;
  int cnt = slot ? 4 : 5;
  int len1 = NB - sr;  // tiles in row sr (bx = sr..63)

  int cur_by = -1;
  float lsum = 0.f;

  for (int jj = 0; jj < cnt; ++jj) {
    int j = start + jj;
    int by, bx;
    if (j < len1) { by = sr;      bx = sr + j; }
    else          { by = 63 - sr; bx = 63 - sr + (j - len1); }
    int row0 = by * 64;
    int col0 = bx * 64;

    if (jj) __syncthreads();          // previous tile's reads done
    bool loadA = (by != cur_by);
    cur_by = by;
#pragma unroll
    for (int i = 0; i < 8; ++i) {     // 2048 16B-chunks per panel / 256 thr
      int idx = i * 256 + tid;
      int r = idx >> 5;               // panel row (512B per row)
      int c = idx & 31;               // 16B chunk within row
      int srcB = ((c ^ (r & 7)) << 4);
      if (loadA) {
        const unsigned char* ga = Xq + (size_t)(row0 + r) * DD + srcB;
        __builtin_amdgcn_global_load_lds(
            (const __attribute__((address_space(1))) void*)ga,
            (__attribute__((address_space(3))) void*)(As + idx * 16), 16, 0, 0);
      }
      const unsigned char* gb = Xq + (size_t)(col0 + r) * DD + srcB;
      __builtin_amdgcn_global_load_lds(
          (const __attribute__((address_space(1))) void*)gb,
          (__attribute__((address_space(3))) void*)(Bs + idx * 16), 16, 0, 0);
    }
    __syncthreads();                  // drain: panels ready

    f32x4 acc[2][2];
#pragma unroll
    for (int m = 0; m < 2; ++m)
#pragma unroll
      for (int n = 0; n < 2; ++n) acc[m][n] = (f32x4){0.f, 0.f, 0.f, 0.f};

#pragma unroll
    for (int ks = 0; ks < 16; ++ks) {  // 16 k-chunks of 32 fp8, barrier-free
      int q = (ks << 1) | (lane >> 5);       // 16B-chunk col in [0,32)
      int o = ((lane >> 4) & 1) << 3;        // 8B half within chunk
      long a[2], b[2];
#pragma unroll
      for (int m = 0; m < 2; ++m) {
        int r = wr * 32 + m * 16 + (lane & 15);
        a[m] = *(const long*)(As + r * 512 + (((q ^ (r & 7)) << 4) | o));
      }
#pragma unroll
      for (int n = 0; n < 2; ++n) {
        int r = wc * 32 + n * 16 + (lane & 15);
        b[n] = *(const long*)(Bs + r * 512 + (((q ^ (r & 7)) << 4) | o));
      }
#pragma unroll
      for (int m = 0; m < 2; ++m)
#pragma unroll
        for (int n = 0; n < 2; ++n)
          acc[m][n] = __builtin_amdgcn_mfma_f32_16x16x32_fp8_fp8(a[m], b[n],
                                                                 acc[m][n], 0, 0, 0);
    }

    // fused epilogue (per tile): gate on d_emb first; triangle/mirror rule
#pragma unroll
    for (int m = 0; m < 2; ++m) {
#pragma unroll
      for (int n = 0; n < 2; ++n) {
#pragma unroll
        for (int jv = 0; jv < 4; ++jv) {
          float s = acc[m][n][jv];
          float de = 1.0f - s;
          if (de < 0.7f) {
            int row = row0 + wr * 32 + m * 16 + ((lane >> 4) * 4 + jv);
            int col = col0 + wc * 32 + n * 16 + (lane & 15);
            if (col >= row) {
              int lr = labels[row], lc = labels[col];
              float dc = Aij[lr * CC + lc];
              if (dc < 0.7f) {
                float d = de - dc;
                lsum += d * d;
              }
              if (col > row) {  // mirrored ordered pair (col,row)
                float dc2 = Aij[lc * CC + lr];
                if (dc2 < 0.7f) {
                  float d = de - dc2;
                  lsum += d * d;
                }
              }
            }
          }
        }
      }
    }
  }

  // block reduce + single atomic
  for (int off = 32; off; off >>= 1) lsum += __shfl_xor(lsum, off);
  __shared__ float red[4];
  if ((tid & 63) == 0) red[w] = lsum;
  __syncthreads();
  if (tid == 0) {
    float v = (red[0] + red[1] + red[2] + red[3]) * (1.0f / ((float)NN * (float)NN));
    if (v != 0.f) atomicAdd(out, v);
  }
}

extern "C" void kernel_launch(void* const* d_in, const int* in_sizes, int n_in,
                              void* d_out, int out_size, void* d_ws, size_t ws_size,
                              hipStream_t stream) {
  const float* embs = (const float*)d_in[0];
  const int* labels = (const int*)d_in[1];
  const float* Aij = (const float*)d_in[2];
  float* out = (float*)d_out;
  unsigned char* Xq = (unsigned char*)d_ws;  // 4096*512 fp8 = 2 MB

  knorm<<<NN / 4, 256, 0, stream>>>(embs, Xq, out);   // fills Xq, zeroes out
  kmain<<<512, 256, 0, stream>>>(Xq, labels, Aij, out);  // 32 super-rows x 16
}

// Round 9
// 26.315 us; speedup vs baseline: 1.0412x; 1.0412x over previous
//
#include <hip/hip_runtime.h>
#include <hip/hip_fp8.h>

#define NN 4096
#define DD 512
#define CC 1000
#define NB 64   // 64x64 tiles -> triangle grid 64*65/2 = 2080 blocks

typedef __attribute__((ext_vector_type(4))) float f32x4;

// ---------------- kernel 1: normalize rows -> fp8 e4m3 X, init out ---------
__global__ __launch_bounds__(256) void knorm(const float* __restrict__ embs,
                                             unsigned char* __restrict__ Xq,
                                             float* __restrict__ out) {
  int tid = threadIdx.x;
  if (blockIdx.x == 0 && tid == 0) out[0] = 0.f;  // stream-ordered before kmain
  int lane = tid & 63;
  int row = blockIdx.x * 4 + (tid >> 6);
  const float* rp = embs + (size_t)row * DD;
  float4 v0 = ((const float4*)rp)[lane * 2];
  float4 v1 = ((const float4*)rp)[lane * 2 + 1];
  float ss = v0.x * v0.x + v0.y * v0.y + v0.z * v0.z + v0.w * v0.w +
             v1.x * v1.x + v1.y * v1.y + v1.z * v1.z + v1.w * v1.w;
  for (int off = 32; off; off >>= 1) ss += __shfl_xor(ss, off);
  float scale = 1.0f / fmaxf(sqrtf(ss), 1e-8f);
  float f[8] = {v0.x, v0.y, v0.z, v0.w, v1.x, v1.y, v1.z, v1.w};
  unsigned long long o = 0;
#pragma unroll
  for (int i = 0; i < 8; ++i) {
    __hip_fp8_e4m3 q(f[i] * scale);  // OCP e4m3fn, RNE
    o |= (unsigned long long)q.__x << (8 * i);
  }
  *(unsigned long long*)(Xq + (size_t)row * DD + lane * 8) = o;
}

// ---------------- kernel 2: triangular fp8 X @ X^T, counted-vmcnt pipeline --
// R7 geometry (64x64 tiles, 2080 triangle blocks, BK=128, both-sides XOR
// swizzle, fp8 16x16x32 MFMA) with the T4 schedule: double-buffered LDS and
// hand-counted vmcnt so a buffer's 4 loads/wave stay in flight across the
// previous buffer's entire compute phase. NO vmcnt(0) until the last K-it
// (R7's __syncthreads exposed the full VMEM latency 4x per block).
// Schedule invariant: each STAGE = exactly 4 global_load_lds per thread, so
// after issuing STAGE(k+1), s_waitcnt vmcnt(4) => STAGE(k) fully landed
// (per-wave, in-order retirement, m135); barrier makes it block-global.
// lgkmcnt(0)+barrier before each overwrite protects in-flight ds_reads.
__global__ __launch_bounds__(256) void kmain(const unsigned char* __restrict__ Xq,
                                             const int* __restrict__ labels,
                                             const float* __restrict__ Aij,
                                             float* __restrict__ out) {
  __shared__ __align__(16) unsigned char As[2][64 * 128];  // 2 x 8 KB
  __shared__ __align__(16) unsigned char Bs[2][64 * 128];  // 2 x 8 KB
  int tid = threadIdx.x;
  int lane = tid & 63;
  int w = tid >> 6;
  int wr = w >> 1, wc = w & 1;

  // decode triangular block index: by = row-block, bx in [by, NB)
  int t = blockIdx.x;
  int by = 0;
  while (t >= (NB - by)) { t -= (NB - by); ++by; }
  int bx = by + t;
  int row0 = by * 64;
  int col0 = bx * 64;

  f32x4 acc[2][2];
#pragma unroll
  for (int m = 0; m < 2; ++m)
#pragma unroll
    for (int n = 0; n < 2; ++n) acc[m][n] = (f32x4){0.f, 0.f, 0.f, 0.f};

// 4 load_lds per thread per STAGE (2 for A, 2 for B)
#define STAGE(b, itv)                                                           \
  {                                                                             \
    int k0_ = (itv) * 128;                                                      \
    _Pragma("unroll") for (int i = 0; i < 2; ++i) {                             \
      int idx = i * 256 + tid;                                                  \
      int r = idx >> 3;                                                         \
      int c = idx & 7;                                                          \
      int srcB = ((c ^ (r & 7)) << 4);                                          \
      const unsigned char* ga = Xq + (size_t)(row0 + r) * DD + k0_ + srcB;      \
      const unsigned char* gb = Xq + (size_t)(col0 + r) * DD + k0_ + srcB;      \
      __builtin_amdgcn_global_load_lds(                                         \
          (const __attribute__((address_space(1))) void*)ga,                    \
          (__attribute__((address_space(3))) void*)(As[b] + idx * 16), 16, 0, 0);\
      __builtin_amdgcn_global_load_lds(                                         \
          (const __attribute__((address_space(1))) void*)gb,                    \
          (__attribute__((address_space(3))) void*)(Bs[b] + idx * 16), 16, 0, 0);\
    }                                                                           \
  }

#define COMPUTE(bf)                                                             \
  {                                                                             \
    _Pragma("unroll") for (int ks = 0; ks < 4; ++ks) {                          \
      int q = (ks << 1) | (lane >> 5);                                          \
      int o = ((lane >> 4) & 1) << 3;                                           \
      long a[2], b[2];                                                          \
      _Pragma("unroll") for (int m = 0; m < 2; ++m) {                           \
        int r = wr * 32 + m * 16 + (lane & 15);                                 \
        a[m] = *(const long*)(As[bf] + r * 128 + (((q ^ (r & 7)) << 4) | o));   \
      }                                                                         \
      _Pragma("unroll") for (int n = 0; n < 2; ++n) {                           \
        int r = wc * 32 + n * 16 + (lane & 15);                                 \
        b[n] = *(const long*)(Bs[bf] + r * 128 + (((q ^ (r & 7)) << 4) | o));   \
      }                                                                         \
      _Pragma("unroll") for (int m = 0; m < 2; ++m)                             \
        _Pragma("unroll") for (int n = 0; n < 2; ++n)                           \
          acc[m][n] = __builtin_amdgcn_mfma_f32_16x16x32_fp8_fp8(               \
              a[m], b[n], acc[m][n], 0, 0, 0);                                  \
    }                                                                           \
  }

  STAGE(0, 0);                                   // in flight: 4 (buf0)
  STAGE(1, 1);                                   // in flight: 8 (buf0,buf1)
  asm volatile("s_waitcnt vmcnt(4)" ::: "memory");   // buf0 landed (mine)
  __builtin_amdgcn_s_barrier();                      // buf0 landed (all waves)
  COMPUTE(0);                                    // buf1 in flight throughout
  asm volatile("s_waitcnt lgkmcnt(0)" ::: "memory"); // my buf0 reads retired
  __builtin_amdgcn_s_barrier();                      // all readers done
  STAGE(0, 2);                                   // overwrite buf0; in flight <=8
  asm volatile("s_waitcnt vmcnt(4)" ::: "memory");   // buf1 landed
  __builtin_amdgcn_s_barrier();
  COMPUTE(1);                                    // buf0-it2 in flight
  asm volatile("s_waitcnt lgkmcnt(0)" ::: "memory");
  __builtin_amdgcn_s_barrier();
  STAGE(1, 3);                                   // overwrite buf1; in flight <=8
  asm volatile("s_waitcnt vmcnt(4)" ::: "memory");   // buf0-it2 landed
  __builtin_amdgcn_s_barrier();
  COMPUTE(0);                                    // buf0 holds it2
  asm volatile("s_waitcnt lgkmcnt(0) vmcnt(0)" ::: "memory");  // buf1-it3 landed
  __builtin_amdgcn_s_barrier();
  COMPUTE(1);                                    // buf1 holds it3

#undef STAGE
#undef COMPUTE

  // fused epilogue: gate on d_emb first (rarely true off-diagonal) so gathers
  // stay behind an exec-masked branch; per-element triangle/mirror rule.
  float lsum = 0.f;
#pragma unroll
  for (int m = 0; m < 2; ++m) {
#pragma unroll
    for (int n = 0; n < 2; ++n) {
#pragma unroll
      for (int jv = 0; jv < 4; ++jv) {
        float s = acc[m][n][jv];
        float de = 1.0f - s;
        if (de < 0.7f) {
          int row = row0 + wr * 32 + m * 16 + ((lane >> 4) * 4 + jv);
          int col = col0 + wc * 32 + n * 16 + (lane & 15);
          if (col >= row) {
            int lr = labels[row], lc = labels[col];
            float dc = Aij[lr * CC + lc];
            if (dc < 0.7f) {
              float d = de - dc;
              lsum += d * d;
            }
            if (col > row) {  // mirrored ordered pair (col,row)
              float dc2 = Aij[lc * CC + lr];
              if (dc2 < 0.7f) {
                float d = de - dc2;
                lsum += d * d;
              }
            }
          }
        }
      }
    }
  }
  for (int off = 32; off; off >>= 1) lsum += __shfl_xor(lsum, off);
  __shared__ float red[4];
  if ((tid & 63) == 0) red[w] = lsum;
  __syncthreads();
  if (tid == 0) {
    float v = (red[0] + red[1] + red[2] + red[3]) * (1.0f / ((float)NN * (float)NN));
    if (v != 0.f) atomicAdd(out, v);
  }
}

extern "C" void kernel_launch(void* const* d_in, const int* in_sizes, int n_in,
                              void* d_out, int out_size, void* d_ws, size_t ws_size,
                              hipStream_t stream) {
  const float* embs = (const float*)d_in[0];
  const int* labels = (const int*)d_in[1];
  const float* Aij = (const float*)d_in[2];
  float* out = (float*)d_out;
  unsigned char* Xq = (unsigned char*)d_ws;  // 4096*512 fp8 = 2 MB

  knorm<<<NN / 4, 256, 0, stream>>>(embs, Xq, out);            // fills Xq, zeroes out
  kmain<<<(NB * (NB + 1)) / 2, 256, 0, stream>>>(Xq, labels, Aij, out);  // triangle
}

// Round 10
// 24.377 us; speedup vs baseline: 1.1240x; 1.0795x over previous
//
#include <hip/hip_runtime.h>
#include <hip/hip_fp8.h>

#define NN 4096
#define DD 512
#define CC 1000
#define NB 64   // 64x64 tiles -> triangle grid 64*65/2 = 2080 blocks

typedef __attribute__((ext_vector_type(4))) float f32x4;
typedef __attribute__((ext_vector_type(4))) int i32x4;
typedef __attribute__((ext_vector_type(8))) int i32x8;

// ---------------- kernel 1: normalize rows -> fp8 e4m3 X, init out ---------
__global__ __launch_bounds__(256) void knorm(const float* __restrict__ embs,
                                             unsigned char* __restrict__ Xq,
                                             float* __restrict__ out) {
  int tid = threadIdx.x;
  if (blockIdx.x == 0 && tid == 0) out[0] = 0.f;  // stream-ordered before kmain
  int lane = tid & 63;
  int row = blockIdx.x * 4 + (tid >> 6);
  const float* rp = embs + (size_t)row * DD;
  float4 v0 = ((const float4*)rp)[lane * 2];
  float4 v1 = ((const float4*)rp)[lane * 2 + 1];
  float ss = v0.x * v0.x + v0.y * v0.y + v0.z * v0.z + v0.w * v0.w +
             v1.x * v1.x + v1.y * v1.y + v1.z * v1.z + v1.w * v1.w;
  for (int off = 32; off; off >>= 1) ss += __shfl_xor(ss, off);
  float scale = 1.0f / fmaxf(sqrtf(ss), 1e-8f);
  float f[8] = {v0.x, v0.y, v0.z, v0.w, v1.x, v1.y, v1.z, v1.w};
  unsigned long long o = 0;
#pragma unroll
  for (int i = 0; i < 8; ++i) {
    __hip_fp8_e4m3 q(f[i] * scale);  // OCP e4m3fn, RNE
    o |= (unsigned long long)q.__x << (8 * i);
  }
  *(unsigned long long*)(Xq + (size_t)row * DD + lane * 8) = o;
}

// ---------------- kernel 2: triangular MX-fp8 X @ X^T -> gated loss ---------
// R7's proven structure verbatim (64x64 tiles, 2080 triangle blocks ~8/CU,
// BK=128, 2-barrier schedule, global_load_lds(16B), both-sides XOR swizzle).
// ONLY change vs R7: the 4 chained mfma_f32_16x16x32_fp8_fp8 per fragment
// become ONE mfma_scale_f32_16x16x128_f8f6f4 (FMT=fp8, e8m0 scales = 1.0):
// 4x fewer MFMA + ds_read instructions, 4x more K per MFMA -- m148 measured
// 1.64x for exactly this swap in exactly this 2-barrier structure.
// Lane k-range widens 8B -> 32B: logical 16B-chunks {2*(lane>>4), +1} of the
// 128B row, each read with the same ((q ^ (r&7))<<4) swizzled ds_read_b128.
// C/D layout is shape-determined (16x16) -> epilogue identical to R7.
__global__ __launch_bounds__(256) void kmain(const unsigned char* __restrict__ Xq,
                                             const int* __restrict__ labels,
                                             const float* __restrict__ Aij,
                                             float* __restrict__ out) {
  __shared__ __align__(16) unsigned char As[64 * 128];  // 64 rows x 128B (BK=128)
  __shared__ __align__(16) unsigned char Bs[64 * 128];
  int tid = threadIdx.x;
  int lane = tid & 63;
  int w = tid >> 6;
  int wr = w >> 1, wc = w & 1;

  // decode triangular block index: by = row-block, bx in [by, NB)
  int t = blockIdx.x;
  int by = 0;
  while (t >= (NB - by)) { t -= (NB - by); ++by; }
  int bx = by + t;
  int row0 = by * 64;
  int col0 = bx * 64;

  f32x4 acc[2][2];
#pragma unroll
  for (int m = 0; m < 2; ++m)
#pragma unroll
    for (int n = 0; n < 2; ++n) acc[m][n] = (f32x4){0.f, 0.f, 0.f, 0.f};

  const int SC1 = 0x7F7F7F7F;  // e8m0 = 127 -> scale 1.0, all byte lanes

  for (int it = 0; it < DD / 128; ++it) {  // 4 K-steps of 128 fp8
    int k0 = it * 128;
    if (it) __syncthreads();
#pragma unroll
    for (int i = 0; i < 2; ++i) {
      int idx = i * 256 + tid;              // 16B chunk index (512 chunks = 16KB)
      int r = idx >> 3;                     // tile row (128B per row)
      int c = idx & 7;                      // 16B chunk within row
      int srcB = ((c ^ (r & 7)) << 4);      // inverse-swizzled source byte
      const unsigned char* ga = Xq + (size_t)(row0 + r) * DD + k0 + srcB;
      const unsigned char* gb = Xq + (size_t)(col0 + r) * DD + k0 + srcB;
      __builtin_amdgcn_global_load_lds(
          (const __attribute__((address_space(1))) void*)ga,
          (__attribute__((address_space(3))) void*)(As + idx * 16), 16, 0, 0);
      __builtin_amdgcn_global_load_lds(
          (const __attribute__((address_space(1))) void*)gb,
          (__attribute__((address_space(3))) void*)(Bs + idx * 16), 16, 0, 0);
    }
    __syncthreads();

    // one K=128 scaled MFMA per fragment pair
    int o2 = (lane >> 4) << 1;              // first logical 16B-chunk (0,2,4,6)
    i32x8 a[2], b[2];
#pragma unroll
    for (int m = 0; m < 2; ++m) {
      int r = wr * 32 + m * 16 + (lane & 15);
      const unsigned char* base = As + r * 128;
      i32x4 lo = *(const i32x4*)(base + ((o2 ^ (r & 7)) << 4));
      i32x4 hi = *(const i32x4*)(base + (((o2 + 1) ^ (r & 7)) << 4));
      a[m][0] = lo[0]; a[m][1] = lo[1]; a[m][2] = lo[2]; a[m][3] = lo[3];
      a[m][4] = hi[0]; a[m][5] = hi[1]; a[m][6] = hi[2]; a[m][7] = hi[3];
    }
#pragma unroll
    for (int n = 0; n < 2; ++n) {
      int r = wc * 32 + n * 16 + (lane & 15);
      const unsigned char* base = Bs + r * 128;
      i32x4 lo = *(const i32x4*)(base + ((o2 ^ (r & 7)) << 4));
      i32x4 hi = *(const i32x4*)(base + (((o2 + 1) ^ (r & 7)) << 4));
      b[n][0] = lo[0]; b[n][1] = lo[1]; b[n][2] = lo[2]; b[n][3] = lo[3];
      b[n][4] = hi[0]; b[n][5] = hi[1]; b[n][6] = hi[2]; b[n][7] = hi[3];
    }
#pragma unroll
    for (int m = 0; m < 2; ++m)
#pragma unroll
      for (int n = 0; n < 2; ++n)
        acc[m][n] = __builtin_amdgcn_mfma_scale_f32_16x16x128_f8f6f4(
            a[m], b[n], acc[m][n], 0 /*cbsz: fp8*/, 0 /*blgp: fp8*/,
            0, SC1, 0, SC1);
  }

  // fused epilogue: gate on d_emb first (rarely true off-diagonal) so gathers
  // stay behind an exec-masked branch; per-element triangle/mirror rule.
  float lsum = 0.f;
#pragma unroll
  for (int m = 0; m < 2; ++m) {
#pragma unroll
    for (int n = 0; n < 2; ++n) {
#pragma unroll
      for (int jv = 0; jv < 4; ++jv) {
        float s = acc[m][n][jv];
        float de = 1.0f - s;
        if (de < 0.7f) {
          int row = row0 + wr * 32 + m * 16 + ((lane >> 4) * 4 + jv);
          int col = col0 + wc * 32 + n * 16 + (lane & 15);
          if (col >= row) {
            int lr = labels[row], lc = labels[col];
            float dc = Aij[lr * CC + lc];
            if (dc < 0.7f) {
              float d = de - dc;
              lsum += d * d;
            }
            if (col > row) {  // mirrored ordered pair (col,row)
              float dc2 = Aij[lc * CC + lr];
              if (dc2 < 0.7f) {
                float d = de - dc2;
                lsum += d * d;
              }
            }
          }
        }
      }
    }
  }
  for (int off = 32; off; off >>= 1) lsum += __shfl_xor(lsum, off);
  __shared__ float red[4];
  if ((tid & 63) == 0) red[w] = lsum;
  __syncthreads();
  if (tid == 0) {
    float v = (red[0] + red[1] + red[2] + red[3]) * (1.0f / ((float)NN * (float)NN));
    if (v != 0.f) atomicAdd(out, v);
  }
}

extern "C" void kernel_launch(void* const* d_in, const int* in_sizes, int n_in,
                              void* d_out, int out_size, void* d_ws, size_t ws_size,
                              hipStream_t stream) {
  const float* embs = (const float*)d_in[0];
  const int* labels = (const int*)d_in[1];
  const float* Aij = (const float*)d_in[2];
  float* out = (float*)d_out;
  unsigned char* Xq = (unsigned char*)d_ws;  // 4096*512 fp8 = 2 MB

  knorm<<<NN / 4, 256, 0, stream>>>(embs, Xq, out);            // fills Xq, zeroes out
  kmain<<<(NB * (NB + 1)) / 2, 256, 0, stream>>>(Xq, labels, Aij, out);  // triangle
}